// Round 7
// baseline (615.657 us; speedup 1.0000x reference)
//
#include <hip/hip_runtime.h>
#include <stdint.h>

typedef __attribute__((ext_vector_type(8))) short bf16x8;
typedef __attribute__((ext_vector_type(4))) float f32x4;
typedef __attribute__((ext_vector_type(8))) unsigned short us8;

static __device__ __forceinline__ unsigned short f2bf_u(float f) {
  __bf16 h = (__bf16)f;
  return __builtin_bit_cast(unsigned short, h);
}
static __device__ __forceinline__ uint32_t pack2bf(float a, float b) {
  return (uint32_t)f2bf_u(a) | ((uint32_t)f2bf_u(b) << 16);
}
static __device__ __forceinline__ float silu_f(float v) {
  float e = __builtin_amdgcn_exp2f(v * -1.44269504088896341f);
  return v * __builtin_amdgcn_rcpf(1.0f + e);
}

// ---------------------------------------------------------------------------
// One MLP layer, x-shared: wave w computes cols [w*16,w*16+16) for all 128
// rows of the tile. src/dst are 32KB bf16 [128][256B] XOR-swizzled LDS.
// Weights for this layer/wave are 4 VGPR-resident fragments (wf[ks]).
// ---------------------------------------------------------------------------
template<bool LAST>
static __device__ __forceinline__ void xlayer(
    const char* __restrict__ src, char* __restrict__ dst,
    const bf16x8* wf, const float* __restrict__ bias,
    float* __restrict__ gout, int l15, int q, int w, int rs)
{
  f32x4 bv;
  if (!LAST) bv = *(const f32x4*)(bias + w * 16 + q * 4);
  #pragma unroll
  for (int rg = 0; rg < 8; ++rg) {
    const int row = rg * 16 + l15;
    f32x4 acc = {0.f, 0.f, 0.f, 0.f};
    #pragma unroll
    for (int ks = 0; ks < 4; ++ks) {
      bf16x8 xf = *(const bf16x8*)(src + ((row * 256 + ks * 64 + q * 16) ^ rs));
      acc = __builtin_amdgcn_mfma_f32_16x16x32_bf16(wf[ks], xf, acc, 0, 0, 0);
    }
    if (!LAST) {
      float v0 = silu_f(acc[0] + bv[0]);
      float v1 = silu_f(acc[1] + bv[1]);
      float v2 = silu_f(acc[2] + bv[2]);
      float v3 = silu_f(acc[3] + bv[3]);
      uint2 u; u.x = pack2bf(v0, v1); u.y = pack2bf(v2, v3);
      *(uint2*)(dst + ((row * 256 + w * 32 + q * 8) ^ rs)) = u;
    } else {
      __builtin_nontemporal_store(acc,
          (f32x4*)(gout + (size_t)row * 128 + w * 16 + q * 4));
    }
  }
}

// ---------------------------------------------------------------------------
// Angle branch: tile = 128 rows/block, 8 waves, x-shared, weights in VGPR.
// LDS: xbA 32K | xbB 32K | aux 16K = 80K -> 2 blocks/CU (16 waves = 4/EU).
// amdgpu_waves_per_eu(4,4) pins the allocator to the 128-VGPR budget that
// matches LDS-limited occupancy (R5/R6: min-only bound -> compiler chose
// 64 VGPRs for 8/EU that LDS can't deliver, spilling ~200MB to scratch).
// ---------------------------------------------------------------------------
__global__ __launch_bounds__(512)
__attribute__((amdgpu_waves_per_eu(4, 4)))
void angle_kernel(
    const float* __restrict__ m_ji, const float* __restrict__ a_sbf,
    const int* __restrict__ kj, const int* __restrict__ ji,
    const float* __restrict__ b1, const float* __restrict__ b2,
    const float* __restrict__ b3,
    const char* __restrict__ wt4, const char* __restrict__ waT,
    float* __restrict__ out)
{
  extern __shared__ char lds[];
  char* xbA = lds;
  char* xbB = lds + 32768;
  char* aux = lds + 65536;
  const int tid = threadIdx.x, lane = tid & 63, w = tid >> 6;
  const int l15 = lane & 15, q = lane >> 4;
  const int rs = (l15 & 7) << 4;
  const size_t tb = (size_t)blockIdx.x * 128;

  // proj weights (8 VGPRs)
  bf16x8 wa0 = *(const bf16x8*)(waT + (w * 2 + 0) * 1024 + lane * 16);
  bf16x8 wa1 = *(const bf16x8*)(waT + (w * 2 + 1) * 1024 + lane * 16);

  // gather indices
  int ikj[8], iji[8];
  #pragma unroll
  for (int g = 0; g < 8; ++g) {
    ikj[g] = kj[tb + g * 16 + l15];
    iji[g] = ji[tb + g * 16 + l15];
  }

  // issue ALL gathers now; keep in flight across the staging phase
  f32x4 pk[8], pj[8];
  #pragma unroll
  for (int g = 0; g < 8; ++g) {
    pk[g] = *(const f32x4*)(m_ji + (size_t)ikj[g] * 128 + w * 16 + q * 4);
    pj[g] = *(const f32x4*)(m_ji + (size_t)iji[g] * 128 + w * 16 + q * 4);
  }
  __builtin_amdgcn_sched_barrier(0);

  // stage a_sbf tile -> aux bf16 frags [128][64] swizzled (pad 42->64)
  {
    const float* src = a_sbf + tb * 42;
    #pragma unroll
    for (int j2 = 0; j2 < 8; ++j2) {
      const int i = tid + j2 * 512;
      const int row = i >> 5, p = i & 31;
      const float* rp = src + row * 42 + p * 2;
      float v0 = (p * 2 < 42) ? __builtin_nontemporal_load(rp) : 0.f;
      float v1 = (p * 2 + 1 < 42) ? __builtin_nontemporal_load(rp + 1) : 0.f;
      *(uint32_t*)(aux + ((row * 128 + p * 4) ^ ((row & 7) << 4))) = pack2bf(v0, v1);
    }
  }
  __syncthreads();

  // proj + gather-gate -> x0 -> xbA
  #pragma unroll
  for (int rg = 0; rg < 8; ++rg) {
    const int row = rg * 16 + l15;
    bf16x8 x0f = *(const bf16x8*)(aux + ((row * 128 + q * 16) ^ rs));
    bf16x8 x1f = *(const bf16x8*)(aux + ((row * 128 + 64 + q * 16) ^ rs));
    f32x4 acc = {0.f, 0.f, 0.f, 0.f};
    acc = __builtin_amdgcn_mfma_f32_16x16x32_bf16(wa0, x0f, acc, 0, 0, 0);
    acc = __builtin_amdgcn_mfma_f32_16x16x32_bf16(wa1, x1f, acc, 0, 0, 0);
    f32x4 g = pk[rg] + pj[rg];
    uint2 u;
    u.x = pack2bf(acc[0] * g[0], acc[1] * g[1]);
    u.y = pack2bf(acc[2] * g[2], acc[3] * g[3]);
    *(uint2*)(xbA + ((row * 256 + w * 32 + q * 8) ^ rs)) = u;
  }
  __builtin_amdgcn_sched_barrier(0);

  // MLP weights loaded only now (pk/pj dead -> fits 128-reg budget);
  // latency hides under the barrier + layer-0 LDS reads.
  bf16x8 wfl[4][4];
  #pragma unroll
  for (int L = 0; L < 4; ++L)
    #pragma unroll
    for (int ks = 0; ks < 4; ++ks)
      wfl[L][ks] = *(const bf16x8*)(wt4 + L * 32768 + (w * 4 + ks) * 1024 + lane * 16);

  __syncthreads();

  xlayer<false>(xbA, xbB, wfl[0], b1, nullptr, l15, q, w, rs);
  __syncthreads();
  xlayer<false>(xbB, xbA, wfl[1], b2, nullptr, l15, q, w, rs);
  __syncthreads();
  xlayer<false>(xbA, xbB, wfl[2], b3, nullptr, l15, q, w, rs);
  __syncthreads();
  xlayer<true>(xbB, nullptr, wfl[3], nullptr, out + tb * 128, l15, q, w, rs);
}

// ---------------------------------------------------------------------------
// Edge branch: same structure; proj is (e_rbf @ We) * m_ji, K padded 6->32.
// ---------------------------------------------------------------------------
__global__ __launch_bounds__(512)
__attribute__((amdgpu_waves_per_eu(4, 4)))
void edge_kernel(
    const float* __restrict__ m_ji, const float* __restrict__ e_rbf,
    const float* __restrict__ b1, const float* __restrict__ b2,
    const float* __restrict__ b3,
    const char* __restrict__ wt4, const char* __restrict__ weT,
    float* __restrict__ out)
{
  extern __shared__ char lds[];
  char* xbA = lds;
  char* xbB = lds + 32768;
  float* auxF = (float*)(lds + 65536);
  const int tid = threadIdx.x, lane = tid & 63, w = tid >> 6;
  const int l15 = lane & 15, q = lane >> 4;
  const int rs = (l15 & 7) << 4;
  const size_t tb = (size_t)blockIdx.x * 128;

  bf16x8 we = *(const bf16x8*)(weT + w * 1024 + lane * 16);

  // issue all m_ji row loads upfront (32 VGPRs), pinned
  f32x4 mr[8];
  #pragma unroll
  for (int g = 0; g < 8; ++g)
    mr[g] = *(const f32x4*)(m_ji + (tb + g * 16 + l15) * 128 + w * 16 + q * 4);
  __builtin_amdgcn_sched_barrier(0);

  // stage e_rbf tile (768 contiguous f32)
  {
    const float* src = e_rbf + tb * 6;
    auxF[tid] = __builtin_nontemporal_load(src + tid);
    const int i2 = tid + 512;
    if (i2 < 768) auxF[i2] = __builtin_nontemporal_load(src + i2);
  }
  __syncthreads();

  // proj + gate -> x0 -> xbA
  #pragma unroll
  for (int rg = 0; rg < 8; ++rg) {
    const int row = rg * 16 + l15;
    bf16x8 ef;
    #pragma unroll
    for (int j = 0; j < 8; ++j) {
      float v = (j < 6) ? auxF[row * 6 + j] : 0.f;
      unsigned short h = (q == 0 && j < 6) ? f2bf_u(v) : (unsigned short)0;
      ef[j] = (short)h;
    }
    f32x4 acc = {0.f, 0.f, 0.f, 0.f};
    acc = __builtin_amdgcn_mfma_f32_16x16x32_bf16(we, ef, acc, 0, 0, 0);
    f32x4 g = mr[rg];
    uint2 u;
    u.x = pack2bf(acc[0] * g[0], acc[1] * g[1]);
    u.y = pack2bf(acc[2] * g[2], acc[3] * g[3]);
    *(uint2*)(xbA + ((row * 256 + w * 32 + q * 8) ^ rs)) = u;
  }
  __builtin_amdgcn_sched_barrier(0);

  bf16x8 wfl[4][4];
  #pragma unroll
  for (int L = 0; L < 4; ++L)
    #pragma unroll
    for (int ks = 0; ks < 4; ++ks)
      wfl[L][ks] = *(const bf16x8*)(wt4 + L * 32768 + (w * 4 + ks) * 1024 + lane * 16);

  __syncthreads();

  xlayer<false>(xbA, xbB, wfl[0], b1, nullptr, l15, q, w, rs);
  __syncthreads();
  xlayer<false>(xbB, xbA, wfl[1], b2, nullptr, l15, q, w, rs);
  __syncthreads();
  xlayer<false>(xbA, xbB, wfl[2], b3, nullptr, l15, q, w, rs);
  __syncthreads();
  xlayer<true>(xbB, nullptr, wfl[3], nullptr, out + tb * 128, l15, q, w, rs);
}

// ---------------------------------------------------------------------------
// Prep: bf16 weights into fragment-linear layouts in d_ws.
//  [0,128K):    edge W1..W4 frags [mat][ct*4+ks][lane]16B
//  [128K,256K): angle W1..W4 frags
//  [256K,272K): Wa proj frags [ct*2+ks][lane]  (K pad 42->64)
//  [272K,276K): We proj frags [ct][lane]       (K pad 6->32)
// frag(lane; n = ct*16+l15, k = ks*32+q*8+j) = W[k][n]
// ---------------------------------------------------------------------------
__global__ void prep_kernel(
    const float* __restrict__ W0, const float* __restrict__ W1,
    const float* __restrict__ W2, const float* __restrict__ W3,
    const float* __restrict__ W4, const float* __restrict__ W5,
    const float* __restrict__ W6, const float* __restrict__ W7,
    const float* __restrict__ Wa, const float* __restrict__ We,
    char* __restrict__ ws)
{
  const int gid = blockIdx.x * 256 + threadIdx.x;
  const int lane = gid & 63;
  const int l15 = lane & 15, q = lane >> 4;
  if (gid < 16384) {
    const int mat = gid >> 11;
    const int ctks = (gid & 2047) >> 6;
    const int n = (ctks >> 2) * 16 + l15;
    const int k0 = (ctks & 3) * 32 + q * 8;
    const float* W;
    switch (mat) {
      case 0: W = W0; break; case 1: W = W1; break;
      case 2: W = W2; break; case 3: W = W3; break;
      case 4: W = W4; break; case 5: W = W5; break;
      case 6: W = W6; break; default: W = W7; break;
    }
    us8 v;
    #pragma unroll
    for (int j = 0; j < 8; ++j) v[j] = f2bf_u(W[(size_t)(k0 + j) * 128 + n]);
    *(us8*)(ws + mat * 32768 + ctks * 1024 + lane * 16) = v;
  } else if (gid < 17408) {
    const int g = gid - 16384;
    const int ctks = g >> 6;
    const int n = (ctks >> 1) * 16 + l15;
    const int k0 = (ctks & 1) * 32 + q * 8;
    us8 v;
    #pragma unroll
    for (int j = 0; j < 8; ++j) {
      const int k = k0 + j;
      v[j] = (k < 42) ? f2bf_u(Wa[(size_t)k * 128 + n]) : (unsigned short)0;
    }
    *(us8*)(ws + 262144 + ctks * 1024 + lane * 16) = v;
  } else if (gid < 17920) {
    const int g = gid - 17408;
    const int ct = g >> 6;
    const int n = ct * 16 + l15;
    const int k0 = q * 8;
    us8 v;
    #pragma unroll
    for (int j = 0; j < 8; ++j) {
      const int k = k0 + j;
      v[j] = (k < 6) ? f2bf_u(We[(size_t)k * 128 + n]) : (unsigned short)0;
    }
    *(us8*)(ws + 278528 + ct * 1024 + lane * 16) = v;
  }
}

extern "C" void kernel_launch(void* const* d_in, const int* in_sizes, int n_in,
                              void* d_out, int out_size, void* d_ws, size_t ws_size,
                              hipStream_t stream) {
  (void)in_sizes; (void)n_in; (void)out_size; (void)ws_size;
  const float* m_ji  = (const float*)d_in[0];
  const float* e_rbf = (const float*)d_in[1];
  const float* a_sbf = (const float*)d_in[2];
  const int*   kj    = (const int*)d_in[4];
  const int*   ji    = (const int*)d_in[5];
  const float* We    = (const float*)d_in[6];
  const float* We1   = (const float*)d_in[7];
  const float* be1   = (const float*)d_in[8];
  const float* We2   = (const float*)d_in[9];
  const float* be2   = (const float*)d_in[10];
  const float* We3   = (const float*)d_in[11];
  const float* be3   = (const float*)d_in[12];
  const float* We4   = (const float*)d_in[13];
  const float* Wa    = (const float*)d_in[14];
  const float* Wa1   = (const float*)d_in[15];
  const float* ba1   = (const float*)d_in[16];
  const float* Wa2   = (const float*)d_in[17];
  const float* ba2   = (const float*)d_in[18];
  const float* Wa3   = (const float*)d_in[19];
  const float* ba3   = (const float*)d_in[20];
  const float* Wa4   = (const float*)d_in[21];
  char* ws = (char*)d_ws;
  float* out = (float*)d_out;

  hipFuncSetAttribute((const void*)edge_kernel,
                      hipFuncAttributeMaxDynamicSharedMemorySize, 68608);
  hipFuncSetAttribute((const void*)angle_kernel,
                      hipFuncAttributeMaxDynamicSharedMemorySize, 81920);

  prep_kernel<<<70, 256, 0, stream>>>(
      We1, We2, We3, We4, Wa1, Wa2, Wa3, Wa4, Wa, We, ws);
  edge_kernel<<<262144 / 128, 512, 68608, stream>>>(
      m_ji, e_rbf, be1, be2, be3, ws, ws + 278528, out);
  angle_kernel<<<1048576 / 128, 512, 81920, stream>>>(
      m_ji, a_sbf, kj, ji, ba1, ba2, ba3, ws + 131072, ws + 262144,
      out + (size_t)262144 * 128);
}

// Round 8
// 525.583 us; speedup vs baseline: 1.1714x; 1.1714x over previous
//
#include <hip/hip_runtime.h>
#include <stdint.h>

typedef __attribute__((ext_vector_type(8))) short bf16x8;
typedef __attribute__((ext_vector_type(4))) float f32x4;
typedef __attribute__((ext_vector_type(8))) unsigned short us8;

#define T_CNT 1048576
#define E_CNT 262144

static __device__ __forceinline__ unsigned short f2bf_u(float f) {
  __bf16 h = (__bf16)f;
  return __builtin_bit_cast(unsigned short, h);
}
static __device__ __forceinline__ uint32_t pack2bf(float a, float b) {
  return (uint32_t)f2bf_u(a) | ((uint32_t)f2bf_u(b) << 16);
}
static __device__ __forceinline__ float silu_f(float v) {
  float e = __builtin_amdgcn_exp2f(v * -1.44269504088896341f);
  return v * __builtin_amdgcn_rcpf(1.0f + e);
}
static __device__ __forceinline__ bf16x8 frag8(f32x4 a, f32x4 b) {
  bf16x8 r;
  r[0] = (short)f2bf_u(a[0]); r[1] = (short)f2bf_u(a[1]);
  r[2] = (short)f2bf_u(a[2]); r[3] = (short)f2bf_u(a[3]);
  r[4] = (short)f2bf_u(b[0]); r[5] = (short)f2bf_u(b[1]);
  r[6] = (short)f2bf_u(b[2]); r[7] = (short)f2bf_u(b[3]);
  return r;
}

// ---------------------------------------------------------------------------
// R8 structure: 256-thread blocks (4 waves), 64-row tiles, 32KB LDS ->
// 5 blocks/CU (20 waves/CU). Wave w owns cols [w*32, w*32+32). x ping-pongs
// through xbA/xbB (XOR-swizzled); weights stream from L2-hot ws fragments.
// No staging phase: proj fragments built directly from global (Wa frags are
// zero for k>=42 so k-tail garbage is harmless; partial loads avoid OOB).
// ---------------------------------------------------------------------------
__global__ __launch_bounds__(256)
__attribute__((amdgpu_waves_per_eu(4, 5)))
void angle_kernel(
    const float* __restrict__ m_ji, const float* __restrict__ a_sbf,
    const int* __restrict__ kj, const int* __restrict__ ji,
    const float* __restrict__ b1, const float* __restrict__ b2,
    const float* __restrict__ b3,
    const char* __restrict__ wt4, const char* __restrict__ waT,
    float* __restrict__ out)
{
  __shared__ __align__(16) char xbA[16384];
  __shared__ __align__(16) char xbB[16384];
  const int tid = threadIdx.x, lane = tid & 63, w = tid >> 6;
  const int l15 = lane & 15, q = lane >> 4;
  const int rs = (l15 & 7) << 4;
  const size_t tb = (size_t)blockIdx.x * 64;
  const int cb = w * 32;

  // proj weight frags wa[ct][ks] (16 VGPRs)
  bf16x8 wa[2][2];
  #pragma unroll
  for (int ct = 0; ct < 2; ++ct)
    #pragma unroll
    for (int ks = 0; ks < 2; ++ks)
      wa[ct][ks] = *(const bf16x8*)(waT + (((w * 2 + ct) * 2 + ks) << 10) + lane * 16);

  // gather indices
  int ikj[4], iji[4];
  #pragma unroll
  for (int g = 0; g < 4; ++g) {
    ikj[g] = kj[tb + g * 16 + l15];
    iji[g] = ji[tb + g * 16 + l15];
  }

  // depth-2 gather pipeline (32 transient VGPRs)
  f32x4 pk[2][2], pj[2][2];
  auto gissue = [&](int g) {
    const float* bk = m_ji + (size_t)ikj[g] * 128 + cb + q * 4;
    const float* bj = m_ji + (size_t)iji[g] * 128 + cb + q * 4;
    pk[g & 1][0] = *(const f32x4*)(bk);
    pk[g & 1][1] = *(const f32x4*)(bk + 16);
    pj[g & 1][0] = *(const f32x4*)(bj);
    pj[g & 1][1] = *(const f32x4*)(bj + 16);
  };
  gissue(0); gissue(1);

  // proj + gate -> x0 -> xbA (no staging barrier; frags straight from global)
  #pragma unroll
  for (int rg = 0; rg < 4; ++rg) {
    const int row = rg * 16 + l15;
    const float* ap = a_sbf + (tb + row) * 42;
    // frag0: k = q*8 + j  (k in 0..31, all real)
    f32x4 a0 = *(const f32x4*)(ap + q * 8);
    f32x4 a1 = *(const f32x4*)(ap + q * 8 + 4);
    // frag1: k = 32 + q*8 + j  (real only for k<42; Wa frag is 0 beyond)
    f32x4 c0 = {0.f, 0.f, 0.f, 0.f}, c1 = {0.f, 0.f, 0.f, 0.f};
    if (q == 0) { c0 = *(const f32x4*)(ap + 32); c1 = *(const f32x4*)(ap + 36); }
    else if (q == 1) { float2 t = *(const float2*)(ap + 40); c0[0] = t.x; c0[1] = t.y; }
    bf16x8 f0 = frag8(a0, a1);
    bf16x8 f1 = frag8(c0, c1);
    f32x4 acc0 = {0.f, 0.f, 0.f, 0.f}, acc1 = {0.f, 0.f, 0.f, 0.f};
    acc0 = __builtin_amdgcn_mfma_f32_16x16x32_bf16(wa[0][0], f0, acc0, 0, 0, 0);
    acc0 = __builtin_amdgcn_mfma_f32_16x16x32_bf16(wa[0][1], f1, acc0, 0, 0, 0);
    acc1 = __builtin_amdgcn_mfma_f32_16x16x32_bf16(wa[1][0], f0, acc1, 0, 0, 0);
    acc1 = __builtin_amdgcn_mfma_f32_16x16x32_bf16(wa[1][1], f1, acc1, 0, 0, 0);
    f32x4 g0 = pk[rg & 1][0] + pj[rg & 1][0];
    f32x4 g1 = pk[rg & 1][1] + pj[rg & 1][1];
    if (rg < 2) gissue(rg + 2);
    uint2 u0, u1;
    u0.x = pack2bf(acc0[0] * g0[0], acc0[1] * g0[1]);
    u0.y = pack2bf(acc0[2] * g0[2], acc0[3] * g0[3]);
    u1.x = pack2bf(acc1[0] * g1[0], acc1[1] * g1[1]);
    u1.y = pack2bf(acc1[2] * g1[2], acc1[3] * g1[3]);
    *(uint2*)(xbA + ((row * 256 + w * 64 + q * 8) ^ rs)) = u0;
    *(uint2*)(xbA + ((row * 256 + w * 64 + 32 + q * 8) ^ rs)) = u1;
  }
  __syncthreads();

  // 4 MLP layers; weights streamed per layer (32 VGPRs, freed between layers)
  #pragma unroll
  for (int L = 0; L < 4; ++L) {
    const char* src = (L & 1) ? xbB : xbA;
    char* dst = (L & 1) ? xbA : xbB;
    bf16x8 wf[2][4];
    #pragma unroll
    for (int ct = 0; ct < 2; ++ct)
      #pragma unroll
      for (int ks = 0; ks < 4; ++ks)
        wf[ct][ks] = *(const bf16x8*)(wt4 + (L << 15) + (((w * 2 + ct) * 4 + ks) << 10) + lane * 16);
    if (L < 3) {
      const float* bp = (L == 0) ? b1 : (L == 1) ? b2 : b3;
      f32x4 bv0 = *(const f32x4*)(bp + cb + q * 4);
      f32x4 bv1 = *(const f32x4*)(bp + cb + 16 + q * 4);
      #pragma unroll
      for (int rg = 0; rg < 4; ++rg) {
        const int row = rg * 16 + l15;
        f32x4 acc0 = {0.f, 0.f, 0.f, 0.f}, acc1 = {0.f, 0.f, 0.f, 0.f};
        #pragma unroll
        for (int ks = 0; ks < 4; ++ks) {
          bf16x8 xf = *(const bf16x8*)(src + ((row * 256 + ks * 64 + q * 16) ^ rs));
          acc0 = __builtin_amdgcn_mfma_f32_16x16x32_bf16(wf[0][ks], xf, acc0, 0, 0, 0);
          acc1 = __builtin_amdgcn_mfma_f32_16x16x32_bf16(wf[1][ks], xf, acc1, 0, 0, 0);
        }
        uint2 u0, u1;
        u0.x = pack2bf(silu_f(acc0[0] + bv0[0]), silu_f(acc0[1] + bv0[1]));
        u0.y = pack2bf(silu_f(acc0[2] + bv0[2]), silu_f(acc0[3] + bv0[3]));
        u1.x = pack2bf(silu_f(acc1[0] + bv1[0]), silu_f(acc1[1] + bv1[1]));
        u1.y = pack2bf(silu_f(acc1[2] + bv1[2]), silu_f(acc1[3] + bv1[3]));
        *(uint2*)(dst + ((row * 256 + w * 64 + q * 8) ^ rs)) = u0;
        *(uint2*)(dst + ((row * 256 + w * 64 + 32 + q * 8) ^ rs)) = u1;
      }
      __syncthreads();
    } else {
      #pragma unroll
      for (int rg = 0; rg < 4; ++rg) {
        const int row = rg * 16 + l15;
        f32x4 acc0 = {0.f, 0.f, 0.f, 0.f}, acc1 = {0.f, 0.f, 0.f, 0.f};
        #pragma unroll
        for (int ks = 0; ks < 4; ++ks) {
          bf16x8 xf = *(const bf16x8*)(src + ((row * 256 + ks * 64 + q * 16) ^ rs));
          acc0 = __builtin_amdgcn_mfma_f32_16x16x32_bf16(wf[0][ks], xf, acc0, 0, 0, 0);
          acc1 = __builtin_amdgcn_mfma_f32_16x16x32_bf16(wf[1][ks], xf, acc1, 0, 0, 0);
        }
        float* op = out + (tb + row) * 128 + cb + q * 4;
        __builtin_nontemporal_store(acc0, (f32x4*)(op));
        __builtin_nontemporal_store(acc1, (f32x4*)(op + 16));
      }
    }
  }
}

// ---------------------------------------------------------------------------
// Edge branch: same structure; proj = (e_rbf @ We) * m_ji, K padded 6->32
// (We frags zero for k>=6; ef built directly from global, partial loads).
// ---------------------------------------------------------------------------
__global__ __launch_bounds__(256)
__attribute__((amdgpu_waves_per_eu(4, 5)))
void edge_kernel(
    const float* __restrict__ m_ji, const float* __restrict__ e_rbf,
    const float* __restrict__ b1, const float* __restrict__ b2,
    const float* __restrict__ b3,
    const char* __restrict__ wt4, const char* __restrict__ weT,
    float* __restrict__ out)
{
  __shared__ __align__(16) char xbA[16384];
  __shared__ __align__(16) char xbB[16384];
  const int tid = threadIdx.x, lane = tid & 63, w = tid >> 6;
  const int l15 = lane & 15, q = lane >> 4;
  const int rs = (l15 & 7) << 4;
  const size_t tb = (size_t)blockIdx.x * 64;
  const int cb = w * 32;

  bf16x8 we[2];
  #pragma unroll
  for (int ct = 0; ct < 2; ++ct)
    we[ct] = *(const bf16x8*)(weT + ((w * 2 + ct) << 10) + lane * 16);

  f32x4 mr[2][2];
  auto missue = [&](int g) {
    const float* bm = m_ji + (tb + g * 16 + l15) * 128 + cb + q * 4;
    mr[g & 1][0] = *(const f32x4*)(bm);
    mr[g & 1][1] = *(const f32x4*)(bm + 16);
  };
  missue(0); missue(1);

  #pragma unroll
  for (int rg = 0; rg < 4; ++rg) {
    const int row = rg * 16 + l15;
    const float* ep = e_rbf + (tb + row) * 6;
    f32x4 a0 = {0.f, 0.f, 0.f, 0.f}, a1 = {0.f, 0.f, 0.f, 0.f};
    if (q == 0) {
      a0 = *(const f32x4*)(ep);
      float2 t = *(const float2*)(ep + 4);
      a1[0] = t.x; a1[1] = t.y;
    }
    bf16x8 ef = frag8(a0, a1);
    f32x4 acc0 = {0.f, 0.f, 0.f, 0.f}, acc1 = {0.f, 0.f, 0.f, 0.f};
    acc0 = __builtin_amdgcn_mfma_f32_16x16x32_bf16(we[0], ef, acc0, 0, 0, 0);
    acc1 = __builtin_amdgcn_mfma_f32_16x16x32_bf16(we[1], ef, acc1, 0, 0, 0);
    f32x4 g0 = mr[rg & 1][0];
    f32x4 g1 = mr[rg & 1][1];
    if (rg < 2) missue(rg + 2);
    uint2 u0, u1;
    u0.x = pack2bf(acc0[0] * g0[0], acc0[1] * g0[1]);
    u0.y = pack2bf(acc0[2] * g0[2], acc0[3] * g0[3]);
    u1.x = pack2bf(acc1[0] * g1[0], acc1[1] * g1[1]);
    u1.y = pack2bf(acc1[2] * g1[2], acc1[3] * g1[3]);
    *(uint2*)(xbA + ((row * 256 + w * 64 + q * 8) ^ rs)) = u0;
    *(uint2*)(xbA + ((row * 256 + w * 64 + 32 + q * 8) ^ rs)) = u1;
  }
  __syncthreads();

  #pragma unroll
  for (int L = 0; L < 4; ++L) {
    const char* src = (L & 1) ? xbB : xbA;
    char* dst = (L & 1) ? xbA : xbB;
    bf16x8 wf[2][4];
    #pragma unroll
    for (int ct = 0; ct < 2; ++ct)
      #pragma unroll
      for (int ks = 0; ks < 4; ++ks)
        wf[ct][ks] = *(const bf16x8*)(wt4 + (L << 15) + (((w * 2 + ct) * 4 + ks) << 10) + lane * 16);
    if (L < 3) {
      const float* bp = (L == 0) ? b1 : (L == 1) ? b2 : b3;
      f32x4 bv0 = *(const f32x4*)(bp + cb + q * 4);
      f32x4 bv1 = *(const f32x4*)(bp + cb + 16 + q * 4);
      #pragma unroll
      for (int rg = 0; rg < 4; ++rg) {
        const int row = rg * 16 + l15;
        f32x4 acc0 = {0.f, 0.f, 0.f, 0.f}, acc1 = {0.f, 0.f, 0.f, 0.f};
        #pragma unroll
        for (int ks = 0; ks < 4; ++ks) {
          bf16x8 xf = *(const bf16x8*)(src + ((row * 256 + ks * 64 + q * 16) ^ rs));
          acc0 = __builtin_amdgcn_mfma_f32_16x16x32_bf16(wf[0][ks], xf, acc0, 0, 0, 0);
          acc1 = __builtin_amdgcn_mfma_f32_16x16x32_bf16(wf[1][ks], xf, acc1, 0, 0, 0);
        }
        uint2 u0, u1;
        u0.x = pack2bf(silu_f(acc0[0] + bv0[0]), silu_f(acc0[1] + bv0[1]));
        u0.y = pack2bf(silu_f(acc0[2] + bv0[2]), silu_f(acc0[3] + bv0[3]));
        u1.x = pack2bf(silu_f(acc1[0] + bv1[0]), silu_f(acc1[1] + bv1[1]));
        u1.y = pack2bf(silu_f(acc1[2] + bv1[2]), silu_f(acc1[3] + bv1[3]));
        *(uint2*)(dst + ((row * 256 + w * 64 + q * 8) ^ rs)) = u0;
        *(uint2*)(dst + ((row * 256 + w * 64 + 32 + q * 8) ^ rs)) = u1;
      }
      __syncthreads();
    } else {
      #pragma unroll
      for (int rg = 0; rg < 4; ++rg) {
        const int row = rg * 16 + l15;
        f32x4 acc0 = {0.f, 0.f, 0.f, 0.f}, acc1 = {0.f, 0.f, 0.f, 0.f};
        #pragma unroll
        for (int ks = 0; ks < 4; ++ks) {
          bf16x8 xf = *(const bf16x8*)(src + ((row * 256 + ks * 64 + q * 16) ^ rs));
          acc0 = __builtin_amdgcn_mfma_f32_16x16x32_bf16(wf[0][ks], xf, acc0, 0, 0, 0);
          acc1 = __builtin_amdgcn_mfma_f32_16x16x32_bf16(wf[1][ks], xf, acc1, 0, 0, 0);
        }
        float* op = out + (tb + row) * 128 + cb + q * 4;
        __builtin_nontemporal_store(acc0, (f32x4*)(op));
        __builtin_nontemporal_store(acc1, (f32x4*)(op + 16));
      }
    }
  }
}

// ---------------------------------------------------------------------------
// Prep: bf16 weights into fragment-linear layouts in d_ws (unchanged).
//  [0,128K):    edge W1..W4 frags [mat][ct*4+ks][lane]16B
//  [128K,256K): angle W1..W4 frags
//  [256K,272K): Wa proj frags [ct*2+ks][lane]  (K pad 42->64)
//  [272K,276K): We proj frags [ct][lane]       (K pad 6->32)
// frag(lane; n = ct*16+l15, k = ks*32+q*8+j) = W[k][n]
// ---------------------------------------------------------------------------
__global__ void prep_kernel(
    const float* __restrict__ W0, const float* __restrict__ W1,
    const float* __restrict__ W2, const float* __restrict__ W3,
    const float* __restrict__ W4, const float* __restrict__ W5,
    const float* __restrict__ W6, const float* __restrict__ W7,
    const float* __restrict__ Wa, const float* __restrict__ We,
    char* __restrict__ ws)
{
  const int gid = blockIdx.x * 256 + threadIdx.x;
  const int lane = gid & 63;
  const int l15 = lane & 15, q = lane >> 4;
  if (gid < 16384) {
    const int mat = gid >> 11;
    const int ctks = (gid & 2047) >> 6;
    const int n = (ctks >> 2) * 16 + l15;
    const int k0 = (ctks & 3) * 32 + q * 8;
    const float* W;
    switch (mat) {
      case 0: W = W0; break; case 1: W = W1; break;
      case 2: W = W2; break; case 3: W = W3; break;
      case 4: W = W4; break; case 5: W = W5; break;
      case 6: W = W6; break; default: W = W7; break;
    }
    us8 v;
    #pragma unroll
    for (int j = 0; j < 8; ++j) v[j] = f2bf_u(W[(size_t)(k0 + j) * 128 + n]);
    *(us8*)(ws + mat * 32768 + ctks * 1024 + lane * 16) = v;
  } else if (gid < 17408) {
    const int g = gid - 16384;
    const int ctks = g >> 6;
    const int n = (ctks >> 1) * 16 + l15;
    const int k0 = (ctks & 1) * 32 + q * 8;
    us8 v;
    #pragma unroll
    for (int j = 0; j < 8; ++j) {
      const int k = k0 + j;
      v[j] = (k < 42) ? f2bf_u(Wa[(size_t)k * 128 + n]) : (unsigned short)0;
    }
    *(us8*)(ws + 262144 + ctks * 1024 + lane * 16) = v;
  } else if (gid < 17920) {
    const int g = gid - 17408;
    const int ct = g >> 6;
    const int n = ct * 16 + l15;
    const int k0 = q * 8;
    us8 v;
    #pragma unroll
    for (int j = 0; j < 8; ++j) {
      const int k = k0 + j;
      v[j] = (k < 6) ? f2bf_u(We[(size_t)k * 128 + n]) : (unsigned short)0;
    }
    *(us8*)(ws + 278528 + ct * 1024 + lane * 16) = v;
  }
}

extern "C" void kernel_launch(void* const* d_in, const int* in_sizes, int n_in,
                              void* d_out, int out_size, void* d_ws, size_t ws_size,
                              hipStream_t stream) {
  (void)in_sizes; (void)n_in; (void)out_size; (void)ws_size;
  const float* m_ji  = (const float*)d_in[0];
  const float* e_rbf = (const float*)d_in[1];
  const float* a_sbf = (const float*)d_in[2];
  const int*   kj    = (const int*)d_in[4];
  const int*   ji    = (const int*)d_in[5];
  const float* We    = (const float*)d_in[6];
  const float* We1   = (const float*)d_in[7];
  const float* be1   = (const float*)d_in[8];
  const float* We2   = (const float*)d_in[9];
  const float* be2   = (const float*)d_in[10];
  const float* We3   = (const float*)d_in[11];
  const float* be3   = (const float*)d_in[12];
  const float* We4   = (const float*)d_in[13];
  const float* Wa    = (const float*)d_in[14];
  const float* Wa1   = (const float*)d_in[15];
  const float* ba1   = (const float*)d_in[16];
  const float* Wa2   = (const float*)d_in[17];
  const float* ba2   = (const float*)d_in[18];
  const float* Wa3   = (const float*)d_in[19];
  const float* ba3   = (const float*)d_in[20];
  const float* Wa4   = (const float*)d_in[21];
  char* ws = (char*)d_ws;
  float* out = (float*)d_out;

  prep_kernel<<<70, 256, 0, stream>>>(
      We1, We2, We3, We4, Wa1, Wa2, Wa3, Wa4, Wa, We, ws);
  edge_kernel<<<E_CNT / 64, 256, 0, stream>>>(
      m_ji, e_rbf, be1, be2, be3, ws, ws + 278528, out);
  angle_kernel<<<T_CNT / 64, 256, 0, stream>>>(
      m_ji, a_sbf, kj, ji, ba1, ba2, ba3, ws + 131072, ws + 262144,
      out + (size_t)E_CNT * 128);
}